// Round 5
// baseline (169.667 us; speedup 1.0000x reference)
//
#include <hip/hip_runtime.h>
#include <hip/hip_bf16.h>

typedef __attribute__((ext_vector_type(8))) short short8;
typedef __attribute__((ext_vector_type(4))) float f32x4;
using u16 = unsigned short;
using u32 = unsigned int;

#define IN_F 4096
#define OUT_F 4096
#define RANK 128

// ---- bf16 pack helpers ----
__device__ inline u32 packi(int a, int b) {  // exact for [-8,7]
    float fa = (float)a, fb = (float)b;
    return (__builtin_bit_cast(u32, fa) >> 16) |
           (__builtin_bit_cast(u32, fb) & 0xFFFF0000u);
}
__device__ inline u32 packf(float a, float b) {  // RNE f32->bf16 pair
    u32 ua = __builtin_bit_cast(u32, a);
    u32 ub = __builtin_bit_cast(u32, b);
    ua = (ua + 0x7FFFu + ((ua >> 16) & 1u)) >> 16;
    ub = (ub + 0x7FFFu + ((ub >> 16) & 1u));
    return ua | (ub & 0xFFFF0000u);
}
__device__ inline u16 f2bf(float f) {
    u32 u = __builtin_bit_cast(u32, f);
    u = (u + 0x7FFFu + ((u >> 16) & 1u)) >> 16;
    return (u16)u;
}

// ws layout: y 64KB | xb 1MB | bt 1MB | at 1MB | wqb 32MB
#define WS_Y 0
#define WS_XB 65536
#define WS_BT (WS_XB + 1048576)
#define WS_AT (WS_BT + 1048576)
#define WS_WQB (WS_AT + 1048576)
#define WS_NEED (WS_WQB + (size_t)33554432)

// ---- prep1: [0,128) x->bf16 | [128,384) A^T->at bf16 | [384,640) B^T->bt
//             [640,896) zero out | [896,904) zero y
__global__ __launch_bounds__(512) void prep1_kernel(
    const float* __restrict__ x, const float* __restrict__ A,
    const float* __restrict__ B, float* __restrict__ outz,
    float* __restrict__ y, u16* __restrict__ xb,
    u16* __restrict__ at, u16* __restrict__ bt) {
    __shared__ float tile[64 * 33];
    int bid = blockIdx.x, tid = threadIdx.x;
    if (bid < 128) {
        const f32x4* xv = (const f32x4*)x;
        int vi = bid * 1024 + tid * 2;
        f32x4 a = xv[vi], b = xv[vi + 1];
        union { u32 u[4]; short8 s; } p;
        p.u[0] = packf(a[0], a[1]); p.u[1] = packf(a[2], a[3]);
        p.u[2] = packf(b[0], b[1]); p.u[3] = packf(b[2], b[3]);
        *(short8*)(xb + (size_t)vi * 4) = p.s;
    } else if (bid < 384) {
        int b2 = bid - 128, kt = b2 >> 2, rt = b2 & 3;
        int k0 = kt * 64, r0 = rt * 32;
        for (int u = tid; u < 2048; u += 512) {
            int row = u >> 5, c = u & 31;
            tile[row * 33 + c] = A[(size_t)(k0 + row) * RANK + r0 + c];
        }
        __syncthreads();
        for (int u = tid; u < 2048; u += 512) {
            int rr = u >> 6, k = u & 63;
            at[(size_t)(r0 + rr) * IN_F + k0 + k] = f2bf(tile[k * 33 + rr]);
        }
    } else if (bid < 640) {
        int b2 = bid - 384, rt = b2 >> 7, ot = b2 & 127;
        int r0 = rt * 64, o0 = ot * 32;
        for (int u = tid; u < 2048; u += 512) {
            int row = u >> 5, c = u & 31;
            tile[row * 33 + c] = B[(size_t)(r0 + row) * OUT_F + o0 + c];
        }
        __syncthreads();
        for (int u = tid; u < 2048; u += 512) {
            int oo = u >> 6, k = u & 63;
            bt[(size_t)(o0 + oo) * RANK + r0 + k] = f2bf(tile[k * 33 + oo]);
        }
    } else if (bid < 896) {
        int idx = (bid - 640) * 512 + tid;
        f32x4 z = {0.f, 0.f, 0.f, 0.f};
        ((f32x4*)outz)[idx] = z;
    } else {
        int idx = (bid - 896) * 512 + tid;
        f32x4 z = {0.f, 0.f, 0.f, 0.f};
        ((f32x4*)y)[idx] = z;
    }
}

// ---- prep2: [0,64) y = xb @ at^T (k-split 16, atomics)
//             [64,576) repack wq -> wqb (fragment order), if do_repack
__global__ __launch_bounds__(512) void prep2_kernel(
    const u16* __restrict__ xb, const u16* __restrict__ at,
    float* __restrict__ y, const int* __restrict__ wq,
    u16* __restrict__ wqb) {
    int bid = blockIdx.x, tid = threadIdx.x;
    int lane = tid & 63, wid = tid >> 6;
    if (bid < 64) {
        int wm = wid >> 1, wn = wid & 1;
        int col = lane & 15, kg = lane >> 4;
        int rt = bid & 3, kq = bid >> 2;
        int r = rt * 32 + wn * 16 + col;
        int k0 = kq * 256;
        const u16* xp0 = xb + (size_t)(wm * 32 + col) * IN_F + k0 + kg * 8;
        const u16* xp1 = xp0 + (size_t)16 * IN_F;
        const u16* ap = at + (size_t)r * IN_F + k0 + kg * 8;
        f32x4 acc0 = {0.f, 0.f, 0.f, 0.f}, acc1 = {0.f, 0.f, 0.f, 0.f};
        #pragma unroll
        for (int k = 0; k < 256; k += 32) {
            short8 bf = *(const short8*)(ap + k);
            short8 a0 = *(const short8*)(xp0 + k);
            short8 a1 = *(const short8*)(xp1 + k);
            acc0 = __builtin_amdgcn_mfma_f32_16x16x32_bf16(a0, bf, acc0, 0, 0, 0);
            acc1 = __builtin_amdgcn_mfma_f32_16x16x32_bf16(a1, bf, acc1, 0, 0, 0);
        }
        int rbase = wm * 32 + kg * 4;
        #pragma unroll
        for (int j = 0; j < 4; ++j) {
            atomicAdd(&y[(rbase + j) * RANK + r], acc0[j]);
            atomicAdd(&y[(rbase + j + 16) * RANK + r], acc1[j]);
        }
    } else {
        // repack: block handles 8 rows (one per wave); wave reads its row
        // lane-contiguously (2KB/iter), writes 16B fragments.
        int r = (bid - 64) * 8 + wid;
        int ntile = r >> 4, col = r & 15;
        const int* rp = wq + (size_t)r * IN_F + lane * 8;
        // dest u16 offset: ntile*65536 + kc*512 + (kg*16+col)*8
        // kc = i*16 + (l>>2), kg = l&3
        u16* dp = wqb + (size_t)ntile * 65536 + (size_t)(lane >> 2) * 512 +
                  (size_t)((lane & 3) * 16 + col) * 8;
        #pragma unroll
        for (int i = 0; i < 8; ++i) {
            int4 wa = *(const int4*)(rp + i * 512);
            int4 wb = *(const int4*)(rp + i * 512 + 4);
            union { u32 u[4]; short8 s; } p;
            p.u[0] = packi(wa.x, wa.y); p.u[1] = packi(wa.z, wa.w);
            p.u[2] = packi(wb.x, wb.y); p.u[3] = packi(wb.z, wb.w);
            *(short8*)(dp + (size_t)i * 16 * 512) = p.s;
        }
    }
}

// ---- shared epilogue ----
__device__ inline void epilogue(
    f32x4& acc0, f32x4& acc1, int o, int m0, int kq, int rbase,
    const float* __restrict__ scale, const float* __restrict__ bias,
    const float* __restrict__ y, const u16* __restrict__ bt,
    float* __restrict__ out, int kg) {
    float s = scale[o];
    #pragma unroll
    for (int j = 0; j < 4; ++j) { acc0[j] *= s; acc1[j] *= s; }
    if (kq == 0) {
        const float* yp0 = y + (size_t)m0 * RANK + kg * 8;
        const float* yp1 = yp0 + 16 * RANK;
        const u16* bp = bt + (size_t)o * RANK + kg * 8;
        #pragma unroll
        for (int ks = 0; ks < RANK; ks += 32) {
            f32x4 ya = *(const f32x4*)(yp0 + ks);
            f32x4 yb = *(const f32x4*)(yp0 + ks + 4);
            f32x4 yc = *(const f32x4*)(yp1 + ks);
            f32x4 yd = *(const f32x4*)(yp1 + ks + 4);
            union { u32 u[4]; short8 s; } af0, af1;
            af0.u[0] = packf(ya[0], ya[1]); af0.u[1] = packf(ya[2], ya[3]);
            af0.u[2] = packf(yb[0], yb[1]); af0.u[3] = packf(yb[2], yb[3]);
            af1.u[0] = packf(yc[0], yc[1]); af1.u[1] = packf(yc[2], yc[3]);
            af1.u[2] = packf(yd[0], yd[1]); af1.u[3] = packf(yd[2], yd[3]);
            short8 bfr = *(const short8*)(bp + ks);
            acc0 = __builtin_amdgcn_mfma_f32_16x16x32_bf16(af0.s, bfr, acc0, 0, 0, 0);
            acc1 = __builtin_amdgcn_mfma_f32_16x16x32_bf16(af1.s, bfr, acc1, 0, 0, 0);
        }
        float bv = bias[o];
        #pragma unroll
        for (int j = 0; j < 4; ++j) { acc0[j] += bv; acc1[j] += bv; }
    }
    float* op = out + (size_t)rbase * OUT_F + o;
    #pragma unroll
    for (int j = 0; j < 4; ++j) {
        atomicAdd(op + (size_t)j * OUT_F, acc0[j]);
        atomicAdd(op + (size_t)(j + 16) * OUT_F, acc1[j]);
    }
}

// ---- main (wqb path): BM=64, BN=64, ksplit=4 -> 512 blocks x 8 waves
// All hot loads lane-contiguous; zero int->bf16 work in loop.
__global__ __launch_bounds__(512) void main_wqb_kernel(
    const u16* __restrict__ xb, const u16* __restrict__ wqb,
    const float* __restrict__ scale, const float* __restrict__ bias,
    const float* __restrict__ y, const u16* __restrict__ bt,
    float* __restrict__ out) {
    int tid = threadIdx.x, lane = tid & 63, wid = tid >> 6;
    int wm = wid >> 2, wn = wid & 3;
    int col = lane & 15, kg = lane >> 4;
    int bid = blockIdx.x;
    int ot = bid & 63, mt = (bid >> 6) & 1, kq = bid >> 7;
    int nt = ot * 4 + wn;
    int o = nt * 16 + col;
    int m0 = mt * 64 + wm * 32 + col;

    const u16* fp = wqb + (size_t)nt * 65536 + (size_t)kq * 32 * 512 + lane * 8;
    const u16* xp0 = xb + (size_t)m0 * IN_F + kq * 1024 + kg * 8;
    const u16* xp1 = xp0 + (size_t)16 * IN_F;

    f32x4 acc0 = {0.f, 0.f, 0.f, 0.f}, acc1 = {0.f, 0.f, 0.f, 0.f};
    #pragma unroll 8
    for (int kc = 0; kc < 32; ++kc) {
        short8 bf = *(const short8*)(fp + kc * 512);
        short8 a0 = *(const short8*)(xp0 + kc * 32);
        short8 a1 = *(const short8*)(xp1 + kc * 32);
        acc0 = __builtin_amdgcn_mfma_f32_16x16x32_bf16(a0, bf, acc0, 0, 0, 0);
        acc1 = __builtin_amdgcn_mfma_f32_16x16x32_bf16(a1, bf, acc1, 0, 0, 0);
    }
    int rbase = mt * 64 + wm * 32 + kg * 4;
    epilogue(acc0, acc1, o, m0, kq, rbase, scale, bias, y, bt, out, kg);
}

// ---- main (direct path, fallback if ws too small): R4 structure
#define KCHUNK 1024
__global__ __launch_bounds__(512, 4) void main_direct_kernel(
    const u16* __restrict__ xb, const int* __restrict__ wq,
    const float* __restrict__ scale, const float* __restrict__ bias,
    const float* __restrict__ y, const u16* __restrict__ bt,
    float* __restrict__ out) {
    int tid = threadIdx.x, lane = tid & 63, wid = tid >> 6;
    int wm = wid >> 2, wn = wid & 3;
    int col = lane & 15, kg = lane >> 4;
    int bid = blockIdx.x;
    int ot = bid & 63, mt = (bid >> 6) & 1, kq = bid >> 7;
    int o = ot * 64 + wn * 16 + col;
    int m0 = mt * 64 + wm * 32 + col;
    int k0 = kq * KCHUNK;

    const int* wp = wq + (size_t)o * IN_F + k0 + kg * 8;
    const u16* xp0 = xb + (size_t)m0 * IN_F + k0 + kg * 8;
    const u16* xp1 = xp0 + (size_t)16 * IN_F;

    f32x4 acc0 = {0.f, 0.f, 0.f, 0.f}, acc1 = {0.f, 0.f, 0.f, 0.f};
    for (int it = 0; it < 32; ++it) {
        int4 wa = *(const int4*)(wp + it * 32);
        int4 wb = *(const int4*)(wp + it * 32 + 4);
        union { u32 u[4]; short8 s; } bf;
        bf.u[0] = packi(wa.x, wa.y); bf.u[1] = packi(wa.z, wa.w);
        bf.u[2] = packi(wb.x, wb.y); bf.u[3] = packi(wb.z, wb.w);
        short8 a0 = *(const short8*)(xp0 + it * 32);
        short8 a1 = *(const short8*)(xp1 + it * 32);
        acc0 = __builtin_amdgcn_mfma_f32_16x16x32_bf16(a0, bf.s, acc0, 0, 0, 0);
        acc1 = __builtin_amdgcn_mfma_f32_16x16x32_bf16(a1, bf.s, acc1, 0, 0, 0);
    }
    int rbase = mt * 64 + wm * 32 + kg * 4;
    epilogue(acc0, acc1, o, m0, kq, rbase, scale, bias, y, bt, out, kg);
}

extern "C" void kernel_launch(void* const* d_in, const int* in_sizes, int n_in,
                              void* d_out, int out_size, void* d_ws, size_t ws_size,
                              hipStream_t stream) {
    const float* x = (const float*)d_in[0];
    const int* wq = (const int*)d_in[1];
    const float* scale = (const float*)d_in[2];
    const float* A = (const float*)d_in[3];
    const float* B = (const float*)d_in[4];
    const float* bias = (const float*)d_in[5];
    float* out = (float*)d_out;

    char* ws = (char*)d_ws;
    float* y = (float*)(ws + WS_Y);
    u16* xb = (u16*)(ws + WS_XB);
    u16* bt = (u16*)(ws + WS_BT);
    u16* at = (u16*)(ws + WS_AT);
    u16* wqb = (u16*)(ws + WS_WQB);

    bool big = ws_size >= WS_NEED;

    prep1_kernel<<<904, 512, 0, stream>>>(x, A, B, out, y, xb, at, bt);
    prep2_kernel<<<big ? 576 : 64, 512, 0, stream>>>(xb, at, y, wq, wqb);
    if (big) {
        main_wqb_kernel<<<512, 512, 0, stream>>>(xb, wqb, scale, bias, y, bt, out);
    } else {
        main_direct_kernel<<<512, 512, 0, stream>>>(xb, wq, scale, bias, y, bt, out);
    }
}